// Round 11
// baseline (259.559 us; speedup 1.0000x reference)
//
#include <hip/hip_runtime.h>
#include <stdint.h>

// Problem constants
#define L_    8192
#define N_    8
#define L2_   2048
#define K_    16

typedef unsigned int uint;
typedef unsigned short ushort;
typedef unsigned long long u64;

// round-to-nearest-even f32 -> bf16 (monotone)
__device__ __forceinline__ ushort f2b(float f){
  uint u = __float_as_uint(f);
  return (ushort)((u + 0x7FFFu + ((u >> 16) & 1u)) >> 16);
}
// monotone float->uint mapping (handles tiny negative self-distances)
__device__ __forceinline__ uint ford(float f){
  uint u = __float_as_uint(f);
  return u ^ ((uint)((int)u >> 31) | 0x80000000u);
}
// inverse of ford
__device__ __forceinline__ float unford(uint u){
  uint v = (u & 0x80000000u) ? (u ^ 0x80000000u) : ~u;
  return __uint_as_float(v);
}

// ---------------- K1: MLP (pipe-segregated GEMMs) + coords prep + keep_coords ----------------
// blocks [0,256): MLP, 64 rows; 512 thr = 8 waves; lane = row, wave wv owns dims
//   [16wv,16wv+16). x row and hn row are pulled into VGPRs BEFORE each GEMM loop so
//   the inner loops are pure s_load(weights)+FMA — no ds/s_load lgkmcnt mixing
//   (SMEM completes out-of-order vs LDS, forcing lgkmcnt(0) drains when mixed).
// blocks [256,384): cF build. blocks [384,480): keep_coords gather.
__global__ __launch_bounds__(512) void mlp_prep_k(const float* __restrict__ feat,
                                                  const float* __restrict__ w1,
                                                  const float* __restrict__ g1,
                                                  const float* __restrict__ b1,
                                                  const float* __restrict__ w2,
                                                  const float* __restrict__ g2,
                                                  const float* __restrict__ b2,
                                                  uint* __restrict__ fBw,
                                                  const float* __restrict__ coords,
                                                  const int* __restrict__ keep,
                                                  float4* __restrict__ cF,
                                                  float* __restrict__ out0){
  int blk = blockIdx.x;
  int tid = threadIdx.x;
  if (blk >= 256){
    if (blk < 384){
      int e = (blk - 256) * 512 + tid;         // e = l*8+n, e < 65536
      int l = e >> 3, n = e & 7;
      const float* cr = coords + (size_t)e * 3;
      float x = cr[0], y = cr[1], z = cr[2];
      float cc;
      {
        #pragma clang fp contract(off)
        cc = x*x + y*y + z*z;                  // matches np sum(c*c,-1): (xx+yy)+zz
      }
      cF[n * L_ + l] = make_float4(x, y, z, cc);
    } else {
      int t = (blk - 384) * 512 + tid;         // t < 49152 = L2*N*3
      int i = t / 24; int rem = t - i * 24;    // (n*3+c)
      out0[t] = coords[(size_t)keep[i] * 24 + rem];
    }
    return;
  }

  __shared__ float hn[128][66];   // hn[k][row] transposed: 2-way bank aliasing (free)
  __shared__ float part[8][64];   // LN partial sums [wave][row]
  int lane = tid & 63;
  int wv = __builtin_amdgcn_readfirstlane(tid >> 6);
  int nbase = wv * 16;
  int rg0 = blk * 64;

  // ---- x row -> VGPRs (per-lane global load; 4 fully-used cachelines/row) ----
  float4 xq[16];
  {
    int rg = rg0 + lane; int l = rg & 2047, nb = rg >> 11;
    const float4* xsrc = (const float4*)(feat + (size_t)((l << 3) + nb) * 64);
    #pragma unroll
    for (int q = 0; q < 16; ++q) xq[q] = xsrc[q];
  }

  // ---- GEMM1: acc[d] = x . w1[nbase+d]; pure s_load weights ----
  float acc[16];
  #pragma unroll
  for (int d = 0; d < 16; ++d) acc[d] = 0.f;
  #pragma unroll 4
  for (int k4 = 0; k4 < 16; ++k4){
    float4 xv = xq[k4];
    #pragma unroll
    for (int d = 0; d < 16; ++d){
      float4 wq = ((const float4*)(w1 + (size_t)(nbase + d) * 64))[k4];
      acc[d] += xv.x*wq.x + xv.y*wq.y + xv.z*wq.z + xv.w*wq.w;
    }
  }

  // ---- LN1 (per-lane partials + 8-wave LDS exchange) ----
  {
    float s = 0.f;
    #pragma unroll
    for (int d = 0; d < 16; ++d) s += acc[d];
    part[wv][lane] = s;
  }
  __syncthreads();
  float tot = 0.f;
  #pragma unroll
  for (int w = 0; w < 8; ++w) tot += part[w][lane];
  float mean = tot * 0.0078125f;
  __syncthreads();                 // WAR on part
  {
    float s2 = 0.f;
    #pragma unroll
    for (int d = 0; d < 16; ++d){ acc[d] -= mean; s2 += acc[d] * acc[d]; }
    part[wv][lane] = s2;
  }
  __syncthreads();
  float tv = 0.f;
  #pragma unroll
  for (int w = 0; w < 8; ++w) tv += part[w][lane];
  float rs = rsqrtf(tv * 0.0078125f + 1e-5f);
  #pragma unroll
  for (int d = 0; d < 16; ++d)
    hn[nbase + d][lane] = acc[d] * rs * g1[nbase + d] + b1[nbase + d];
  __syncthreads();                 // hn complete (also WAR on part)

  // ---- hn row -> VGPRs (b32 transposed reads, then one lgkm drain) ----
  float hr[128];
  #pragma unroll
  for (int k = 0; k < 128; ++k) hr[k] = hn[k][lane];

  // ---- GEMM2: a2[d] = hr . w2[nbase+d]; pure s_load weights ----
  float a2[16];
  #pragma unroll
  for (int d = 0; d < 16; ++d) a2[d] = 0.f;
  #pragma unroll 4
  for (int k4 = 0; k4 < 32; ++k4){
    float x0 = hr[k4*4+0], x1 = hr[k4*4+1], x2 = hr[k4*4+2], x3 = hr[k4*4+3];
    #pragma unroll
    for (int d = 0; d < 16; ++d){
      float4 wq = ((const float4*)(w2 + (size_t)(nbase + d) * 128))[k4];
      a2[d] += x0*wq.x + x1*wq.y + x2*wq.z + x3*wq.w;
    }
  }

  // ---- LN2 + ReLU + bf16 pack ----
  {
    float s = 0.f;
    #pragma unroll
    for (int d = 0; d < 16; ++d) s += a2[d];
    part[wv][lane] = s;
  }
  __syncthreads();
  float tot2 = 0.f;
  #pragma unroll
  for (int w = 0; w < 8; ++w) tot2 += part[w][lane];
  float mean2 = tot2 * 0.0078125f;
  __syncthreads();
  {
    float s2 = 0.f;
    #pragma unroll
    for (int d = 0; d < 16; ++d){ a2[d] -= mean2; s2 += a2[d] * a2[d]; }
    part[wv][lane] = s2;
  }
  __syncthreads();
  float tv2 = 0.f;
  #pragma unroll
  for (int w = 0; w < 8; ++w) tv2 += part[w][lane];
  float rs2 = rsqrtf(tv2 * 0.0078125f + 1e-5f);

  uint* orow = fBw + (size_t)(rg0 + lane) * 64 + (nbase >> 1);
  #pragma unroll
  for (int p = 0; p < 8; ++p){
    float o0 = fmaxf(a2[2*p]   * rs2 * g2[nbase+2*p]   + b2[nbase+2*p],   0.f);
    float o1 = fmaxf(a2[2*p+1] * rs2 * g2[nbase+2*p+1] + b2[nbase+2*p+1], 0.f);
    orow[p] = (uint)f2b(o0) | ((uint)f2b(o1) << 16);
  }
}

// ---------------- K2: fused KNN top-16 + gather/max-pool (R8-exact config) ----------------
__device__ __forceinline__ u64 shfl64(u64 v, int src){
  int lo = __shfl((int)(uint)v, src, 64);
  int hi = __shfl((int)(uint)(v >> 32), src, 64);
  return ((u64)(uint)hi << 32) | (uint)lo;
}

__device__ __forceinline__ u64 bsort64(u64 key, int lane){
  #pragma unroll
  for (int k = 2; k <= 64; k <<= 1){
    #pragma unroll
    for (int j = k >> 1; j > 0; j >>= 1){
      u64 o = shfl64(key, lane ^ j);
      bool lower = (lane & j) == 0;
      bool down  = (lane & k) == 0;
      bool takeMin = (lower == down);
      bool oLess = o < key;
      key = (oLess == takeMin) ? o : key;
    }
  }
  return key;
}
__device__ __forceinline__ u64 bmerge64(u64 key, int lane){
  #pragma unroll
  for (int j = 32; j > 0; j >>= 1){
    u64 o = shfl64(key, lane ^ j);
    bool lower = (lane & j) == 0;
    bool oLess = o < key;
    key = (oLess == lower) ? o : key;
  }
  return key;
}

__device__ __forceinline__ u64 drain(u64* ldsq, int& qcount, float& hf, int lane){
  u64 a = (lane < qcount) ? ldsq[lane] : ~0ull;
  a = bsort64(a, lane);
  if (qcount > 64){
    u64 b = (64 + lane < qcount) ? ldsq[64 + lane] : ~0ull;
    b = bsort64(b, lane);
    u64 br = shfl64(b, 63 - lane);
    a = a < br ? a : br;
    a = bmerge64(a, lane);
  }
  if (lane < 16) ldsq[lane] = a;
  u64 h = shfl64(a, 15);
  hf = unford((uint)(h >> 32));
  qcount = 16;
  return a;
}

__global__ __launch_bounds__(256) void knn_pool_k(const float4* __restrict__ cF,
                                                  const int* __restrict__ keep,
                                                  const uint* __restrict__ fB32,
                                                  float* __restrict__ out1){
  __shared__ u64 q8[4][128];
  int tid = threadIdx.x, lane = tid & 63;
  int wv = tid >> 6;
  int g = blockIdx.x * 4 + wv;
  int n = g >> 11, i = g & 2047;
  u64* ldsq = q8[wv];
  int kidx = keep[i];
  float4 qf = cF[(n << 13) + kidx];
  const float4* base = cF + (n << 13);

  float hf  = 3.4e38f;
  float hfr = 3.4e38f;
  int qcount = 0;

  #define PROC(cf, jidx) { \
    float dotf = __builtin_fmaf(qf.x,(cf).x, __builtin_fmaf(qf.y,(cf).y, qf.z*(cf).z)); \
    float d2f  = __builtin_fmaf(-2.0f, dotf, qf.w + (cf).w); \
    bool pred = d2f <= hfr; \
    u64 bal = __ballot(pred); \
    if (bal){ \
      if (pred){ \
        float d2; \
        { \
          _Pragma("clang fp contract(off)") \
          float dot = qf.x*(cf).x + qf.y*(cf).y + qf.z*(cf).z; \
          d2 = (qf.w + (cf).w) - 2.0f * dot; \
        } \
        u64 key = ((u64)ford(d2) << 32) | (uint)(jidx); \
        int rel = __builtin_amdgcn_mbcnt_lo((uint)bal, 0); \
        rel = __builtin_amdgcn_mbcnt_hi((uint)(bal >> 32), rel); \
        ldsq[qcount + rel] = key; \
      } \
      qcount += __popcll(bal); \
      if (qcount >= 49){ drain(ldsq, qcount, hf, lane); hfr = hf + 1e-3f; } \
    } \
  }

  for (int b = 0; b < 128; b += 4){
    const float4* p = base + (b << 6) + lane;
    float4 c0 = p[0];
    float4 c1 = p[64];
    float4 c2 = p[128];
    float4 c3 = p[192];
    int j0 = (b << 6) + lane;
    PROC(c0, j0);
    PROC(c1, j0 + 64);
    PROC(c2, j0 + 128);
    PROC(c3, j0 + 192);
  }
  u64 a = drain(ldsq, qcount, hf, lane);
  #undef PROC

  const uint* frow = fB32 + ((size_t)(n << 11) << 6);
  float m0 = -3.4e38f, m1 = -3.4e38f;
  #pragma unroll
  for (int k = 0; k < 16; ++k){
    int idx = (int)(shfl64(a, k) & 2047u);
    uint u = frow[((size_t)idx << 6) + lane];
    float f0 = __uint_as_float((u & 0xFFFFu) << 16);
    float f1 = __uint_as_float((u >> 16) << 16);
    m0 = fmaxf(m0, f0); m1 = fmaxf(m1, f1);
  }
  float2* o2 = (float2*)(out1 + (size_t)(i * 8 + n) * 128);
  o2[lane] = make_float2(m0, m1);
}

extern "C" void kernel_launch(void* const* d_in, const int* in_sizes, int n_in,
                              void* d_out, int out_size, void* d_ws, size_t ws_size,
                              hipStream_t stream){
  const float* coords = (const float*)d_in[0];
  const float* feat   = (const float*)d_in[1];
  const float* w1     = (const float*)d_in[2];
  const float* g1     = (const float*)d_in[3];
  const float* b1     = (const float*)d_in[4];
  const float* w2     = (const float*)d_in[5];
  const float* g2     = (const float*)d_in[6];
  const float* b2     = (const float*)d_in[7];
  const int*   keep   = (const int*)d_in[8];
  float* out0 = (float*)d_out;                    // keep_coords [2048,8,3]
  float* out1 = out0 + 49152;                     // pool_features [2048,8,128]

  char* ws = (char*)d_ws;
  float4* cF = (float4*)ws;                       // [N][L] f32x4 : 1 MB
  ushort* fB = (ushort*)(ws + (1 << 20));         // [N][L2][128] bf16 : 4 MB

  hipLaunchKernelGGL(mlp_prep_k, dim3(480), dim3(512), 0, stream,
                     feat, w1, g1, b1, w2, g2, b2, (uint*)fB, coords, keep, cF, out0);
  hipLaunchKernelGGL(knn_pool_k, dim3(4096), dim3(256), 0, stream,
                     cF, keep, (const uint*)fB, out1);
}

// Round 12
// 180.297 us; speedup vs baseline: 1.4396x; 1.4396x over previous
//
#include <hip/hip_runtime.h>
#include <stdint.h>

// Problem constants
#define L_    8192
#define N_    8
#define L2_   2048
#define K_    16

typedef unsigned int uint;
typedef unsigned short ushort;
typedef unsigned long long u64;
typedef __attribute__((ext_vector_type(8))) short bh8;   // 8 bf16 (4 VGPRs)
typedef __attribute__((ext_vector_type(4))) float f32x4; // MFMA C/D

// round-to-nearest-even f32 -> bf16 (monotone)
__device__ __forceinline__ ushort f2b(float f){
  uint u = __float_as_uint(f);
  return (ushort)((u + 0x7FFFu + ((u >> 16) & 1u)) >> 16);
}
// monotone float->uint mapping (handles tiny negative self-distances)
__device__ __forceinline__ uint ford(float f){
  uint u = __float_as_uint(f);
  return u ^ ((uint)((int)u >> 31) | 0x80000000u);
}
// inverse of ford
__device__ __forceinline__ float unford(uint u){
  uint v = (u & 0x80000000u) ? (u ^ 0x80000000u) : ~u;
  return __uint_as_float(v);
}

__device__ __forceinline__ void ld8(float* t, const float* p){
  float4 a = *(const float4*)p; float4 b = *(const float4*)(p + 4);
  t[0]=a.x; t[1]=a.y; t[2]=a.z; t[3]=a.w; t[4]=b.x; t[5]=b.y; t[6]=b.z; t[7]=b.w;
}
__device__ __forceinline__ bh8 pack8(const float* v){
  bh8 r;
  #pragma unroll
  for (int j = 0; j < 8; ++j) r[j] = (short)f2b(v[j]);
  return r;
}

// ---------------- K1: MFMA MLP + coords prep + keep_coords ----------------
// blocks [0,256): MLP. 256 thr = 4 independent waves; wave = 16 rows x 128 dims.
//   GEMM1/GEMM2 on v_mfma_f32_16x16x32_bf16; LN in-register (width-16 shfl_xor);
//   GEMM1->GEMM2 A-layout transform via per-wave LDS (bf16, stride 136 = 16B-aligned).
//   No __syncthreads anywhere in the MLP path (waves fully independent).
// blocks [256,512): cF build. blocks [512,704): keep_coords gather.
__global__ __launch_bounds__(256) void mlp_prep_k(const float* __restrict__ feat,
                                                  const float* __restrict__ w1,
                                                  const float* __restrict__ g1,
                                                  const float* __restrict__ b1,
                                                  const float* __restrict__ w2,
                                                  const float* __restrict__ g2,
                                                  const float* __restrict__ b2,
                                                  uint* __restrict__ fBw,
                                                  const float* __restrict__ coords,
                                                  const int* __restrict__ keep,
                                                  float4* __restrict__ cF,
                                                  float* __restrict__ out0){
  int blk = blockIdx.x;
  int tid = threadIdx.x;
  if (blk >= 256){
    if (blk < 512){
      int e = (blk - 256) * 256 + tid;         // e = l*8+n, e < 65536
      int l = e >> 3, n = e & 7;
      const float* cr = coords + (size_t)e * 3;
      float x = cr[0], y = cr[1], z = cr[2];
      float cc;
      {
        #pragma clang fp contract(off)
        cc = x*x + y*y + z*z;                  // matches np sum(c*c,-1): (xx+yy)+zz
      }
      cF[n * L_ + l] = make_float4(x, y, z, cc);
    } else {
      int t = (blk - 512) * 256 + tid;         // t < 49152 = L2*N*3
      int i = t / 24; int rem = t - i * 24;    // (n*3+c)
      out0[t] = coords[(size_t)keep[i] * 24 + rem];
    }
    return;
  }

  __shared__ ushort hlds[64 * 136];            // 17.4 KB; wave wv owns rows [16wv,16wv+16)
  int lane = tid & 63;
  int wv = __builtin_amdgcn_readfirstlane(tid >> 6);
  int quad = lane >> 4, c = lane & 15;
  int rowg = blk * 64 + wv * 16;               // wave's first row (row = n*2048 + l)

  // ---- A-frags for GEMM1: x[rowg+c][s*32 + quad*8 + j], s=0,1 ----
  bh8 a1[2];
  {
    int rg = rowg + c; int l = rg & 2047, nb = rg >> 11;
    const float* xr = feat + (size_t)((l << 3) + nb) * 64 + quad * 8;
    float t[8];
    ld8(t, xr);      a1[0] = pack8(t);
    ld8(t, xr + 32); a1[1] = pack8(t);
  }

  // ---- GEMM1: h[m][n] = sum_k x[m][k] w1[n][k]; B-frag = w1 row slice ----
  f32x4 acc1[8];
  #pragma unroll
  for (int t = 0; t < 8; ++t) acc1[t] = (f32x4){0.f, 0.f, 0.f, 0.f};
  #pragma unroll
  for (int s = 0; s < 2; ++s){
    #pragma unroll
    for (int t = 0; t < 8; ++t){
      float tmp[8];
      ld8(tmp, w1 + (size_t)(t * 16 + c) * 64 + s * 32 + quad * 8);
      acc1[t] = __builtin_amdgcn_mfma_f32_16x16x32_bf16(a1[s], pack8(tmp), acc1[t], 0, 0, 0);
    }
  }

  // ---- LN1 in-register: row m = quad*4+r lives in the 16 lanes of this quad ----
  float mean1[4], rstd1[4];
  #pragma unroll
  for (int r = 0; r < 4; ++r){
    float s = 0.f;
    #pragma unroll
    for (int t = 0; t < 8; ++t) s += acc1[t][r];
    #pragma unroll
    for (int m = 1; m < 16; m <<= 1) s += __shfl_xor(s, m, 16);
    mean1[r] = s * 0.0078125f;
  }
  #pragma unroll
  for (int r = 0; r < 4; ++r){
    float s = 0.f;
    #pragma unroll
    for (int t = 0; t < 8; ++t){ float d = acc1[t][r] - mean1[r]; s += d * d; }
    #pragma unroll
    for (int m = 1; m < 16; m <<= 1) s += __shfl_xor(s, m, 16);
    rstd1[r] = rsqrtf(s * 0.0078125f + 1e-5f);
  }
  ushort* hl = hlds + wv * 16 * 136;
  #pragma unroll
  for (int t = 0; t < 8; ++t){
    float gv = g1[t * 16 + c], bv = b1[t * 16 + c];
    #pragma unroll
    for (int r = 0; r < 4; ++r){
      float v = (acc1[t][r] - mean1[r]) * rstd1[r] * gv + bv;
      hl[(quad * 4 + r) * 136 + t * 16 + c] = f2b(v);
    }
  }

  // ---- GEMM2: A-frags from LDS (layout transform), B = w2 row slices ----
  f32x4 acc2[8];
  #pragma unroll
  for (int t = 0; t < 8; ++t) acc2[t] = (f32x4){0.f, 0.f, 0.f, 0.f};
  #pragma unroll
  for (int s = 0; s < 4; ++s){
    bh8 af = *(const bh8*)(hl + c * 136 + s * 32 + quad * 8);   // 16B-aligned
    #pragma unroll
    for (int t = 0; t < 8; ++t){
      float tmp[8];
      ld8(tmp, w2 + (size_t)(t * 16 + c) * 128 + s * 32 + quad * 8);
      acc2[t] = __builtin_amdgcn_mfma_f32_16x16x32_bf16(af, pack8(tmp), acc2[t], 0, 0, 0);
    }
  }

  // ---- LN2 + ReLU ----
  float mean2[4], rstd2[4];
  #pragma unroll
  for (int r = 0; r < 4; ++r){
    float s = 0.f;
    #pragma unroll
    for (int t = 0; t < 8; ++t) s += acc2[t][r];
    #pragma unroll
    for (int m = 1; m < 16; m <<= 1) s += __shfl_xor(s, m, 16);
    mean2[r] = s * 0.0078125f;
  }
  #pragma unroll
  for (int r = 0; r < 4; ++r){
    float s = 0.f;
    #pragma unroll
    for (int t = 0; t < 8; ++t){ float d = acc2[t][r] - mean2[r]; s += d * d; }
    #pragma unroll
    for (int m = 1; m < 16; m <<= 1) s += __shfl_xor(s, m, 16);
    rstd2[r] = rsqrtf(s * 0.0078125f + 1e-5f);
  }
  #pragma unroll
  for (int t = 0; t < 8; ++t){
    float gv = g2[t * 16 + c], bv = b2[t * 16 + c];
    #pragma unroll
    for (int r = 0; r < 4; ++r){
      float v = fmaxf((acc2[t][r] - mean2[r]) * rstd2[r] * gv + bv, 0.f);
      hl[(quad * 4 + r) * 136 + t * 16 + c] = f2b(v);
    }
  }

  // ---- coalesced store: lane -> row16 = lane>>2, dword-chunk = lane&3 ----
  {
    int row16 = lane >> 2, chunk = lane & 3;
    const uint* src = (const uint*)hlds + (wv * 16 + row16) * 68 + chunk * 16;
    uint* dst = fBw + (size_t)(rowg + row16) * 64 + chunk * 16;
    #pragma unroll
    for (int j = 0; j < 4; ++j)
      *(uint4*)(dst + j * 4) = *(const uint4*)(src + j * 4);
  }
}

// ---------------- K2: fused KNN top-16 + gather/max-pool (R8-exact config) ----------------
__device__ __forceinline__ u64 shfl64(u64 v, int src){
  int lo = __shfl((int)(uint)v, src, 64);
  int hi = __shfl((int)(uint)(v >> 32), src, 64);
  return ((u64)(uint)hi << 32) | (uint)lo;
}

__device__ __forceinline__ u64 bsort64(u64 key, int lane){
  #pragma unroll
  for (int k = 2; k <= 64; k <<= 1){
    #pragma unroll
    for (int j = k >> 1; j > 0; j >>= 1){
      u64 o = shfl64(key, lane ^ j);
      bool lower = (lane & j) == 0;
      bool down  = (lane & k) == 0;
      bool takeMin = (lower == down);
      bool oLess = o < key;
      key = (oLess == takeMin) ? o : key;
    }
  }
  return key;
}
__device__ __forceinline__ u64 bmerge64(u64 key, int lane){
  #pragma unroll
  for (int j = 32; j > 0; j >>= 1){
    u64 o = shfl64(key, lane ^ j);
    bool lower = (lane & j) == 0;
    bool oLess = o < key;
    key = (oLess == lower) ? o : key;
  }
  return key;
}

__device__ __forceinline__ u64 drain(u64* ldsq, int& qcount, float& hf, int lane){
  u64 a = (lane < qcount) ? ldsq[lane] : ~0ull;
  a = bsort64(a, lane);
  if (qcount > 64){
    u64 b = (64 + lane < qcount) ? ldsq[64 + lane] : ~0ull;
    b = bsort64(b, lane);
    u64 br = shfl64(b, 63 - lane);
    a = a < br ? a : br;
    a = bmerge64(a, lane);
  }
  if (lane < 16) ldsq[lane] = a;
  u64 h = shfl64(a, 15);
  hf = unford((uint)(h >> 32));
  qcount = 16;
  return a;
}

__global__ __launch_bounds__(256) void knn_pool_k(const float4* __restrict__ cF,
                                                  const int* __restrict__ keep,
                                                  const uint* __restrict__ fB32,
                                                  float* __restrict__ out1){
  __shared__ u64 q8[4][128];
  int tid = threadIdx.x, lane = tid & 63;
  int wv = tid >> 6;
  int g = blockIdx.x * 4 + wv;
  int n = g >> 11, i = g & 2047;
  u64* ldsq = q8[wv];
  int kidx = keep[i];
  float4 qf = cF[(n << 13) + kidx];
  const float4* base = cF + (n << 13);

  float hf  = 3.4e38f;
  float hfr = 3.4e38f;
  int qcount = 0;

  #define PROC(cf, jidx) { \
    float dotf = __builtin_fmaf(qf.x,(cf).x, __builtin_fmaf(qf.y,(cf).y, qf.z*(cf).z)); \
    float d2f  = __builtin_fmaf(-2.0f, dotf, qf.w + (cf).w); \
    bool pred = d2f <= hfr; \
    u64 bal = __ballot(pred); \
    if (bal){ \
      if (pred){ \
        float d2; \
        { \
          _Pragma("clang fp contract(off)") \
          float dot = qf.x*(cf).x + qf.y*(cf).y + qf.z*(cf).z; \
          d2 = (qf.w + (cf).w) - 2.0f * dot; \
        } \
        u64 key = ((u64)ford(d2) << 32) | (uint)(jidx); \
        int rel = __builtin_amdgcn_mbcnt_lo((uint)bal, 0); \
        rel = __builtin_amdgcn_mbcnt_hi((uint)(bal >> 32), rel); \
        ldsq[qcount + rel] = key; \
      } \
      qcount += __popcll(bal); \
      if (qcount >= 49){ drain(ldsq, qcount, hf, lane); hfr = hf + 1e-3f; } \
    } \
  }

  for (int b = 0; b < 128; b += 4){
    const float4* p = base + (b << 6) + lane;
    float4 c0 = p[0];
    float4 c1 = p[64];
    float4 c2 = p[128];
    float4 c3 = p[192];
    int j0 = (b << 6) + lane;
    PROC(c0, j0);
    PROC(c1, j0 + 64);
    PROC(c2, j0 + 128);
    PROC(c3, j0 + 192);
  }
  u64 a = drain(ldsq, qcount, hf, lane);
  #undef PROC

  const uint* frow = fB32 + ((size_t)(n << 11) << 6);
  float m0 = -3.4e38f, m1 = -3.4e38f;
  #pragma unroll
  for (int k = 0; k < 16; ++k){
    int idx = (int)(shfl64(a, k) & 2047u);
    uint u = frow[((size_t)idx << 6) + lane];
    float f0 = __uint_as_float((u & 0xFFFFu) << 16);
    float f1 = __uint_as_float((u >> 16) << 16);
    m0 = fmaxf(m0, f0); m1 = fmaxf(m1, f1);
  }
  float2* o2 = (float2*)(out1 + (size_t)(i * 8 + n) * 128);
  o2[lane] = make_float2(m0, m1);
}

extern "C" void kernel_launch(void* const* d_in, const int* in_sizes, int n_in,
                              void* d_out, int out_size, void* d_ws, size_t ws_size,
                              hipStream_t stream){
  const float* coords = (const float*)d_in[0];
  const float* feat   = (const float*)d_in[1];
  const float* w1     = (const float*)d_in[2];
  const float* g1     = (const float*)d_in[3];
  const float* b1     = (const float*)d_in[4];
  const float* w2     = (const float*)d_in[5];
  const float* g2     = (const float*)d_in[6];
  const float* b2     = (const float*)d_in[7];
  const int*   keep   = (const int*)d_in[8];
  float* out0 = (float*)d_out;                    // keep_coords [2048,8,3]
  float* out1 = out0 + 49152;                     // pool_features [2048,8,128]

  char* ws = (char*)d_ws;
  float4* cF = (float4*)ws;                       // [N][L] f32x4 : 1 MB
  ushort* fB = (ushort*)(ws + (1 << 20));         // [N][L2][128] bf16 : 4 MB

  hipLaunchKernelGGL(mlp_prep_k, dim3(704), dim3(256), 0, stream,
                     feat, w1, g1, b1, w2, g2, b2, (uint*)fB, coords, keep, cF, out0);
  hipLaunchKernelGGL(knn_pool_k, dim3(4096), dim3(256), 0, stream,
                     cF, keep, (const uint*)fB, out1);
}

// Round 13
// 179.465 us; speedup vs baseline: 1.4463x; 1.0046x over previous
//
#include <hip/hip_runtime.h>
#include <stdint.h>

// Problem constants
#define L_    8192
#define N_    8
#define L2_   2048
#define K_    16

typedef unsigned int uint;
typedef unsigned short ushort;
typedef unsigned long long u64;
typedef __attribute__((ext_vector_type(8))) short bh8;   // 8 bf16 (4 VGPRs)
typedef __attribute__((ext_vector_type(4))) float f32x4; // MFMA C/D

// round-to-nearest-even f32 -> bf16 (monotone)
__device__ __forceinline__ ushort f2b(float f){
  uint u = __float_as_uint(f);
  return (ushort)((u + 0x7FFFu + ((u >> 16) & 1u)) >> 16);
}
// monotone float->uint mapping (handles tiny negative self-distances)
__device__ __forceinline__ uint ford(float f){
  uint u = __float_as_uint(f);
  return u ^ ((uint)((int)u >> 31) | 0x80000000u);
}
// inverse of ford
__device__ __forceinline__ float unford(uint u){
  uint v = (u & 0x80000000u) ? (u ^ 0x80000000u) : ~u;
  return __uint_as_float(v);
}

__device__ __forceinline__ void ld8(float* t, const float* p){
  float4 a = *(const float4*)p; float4 b = *(const float4*)(p + 4);
  t[0]=a.x; t[1]=a.y; t[2]=a.z; t[3]=a.w; t[4]=b.x; t[5]=b.y; t[6]=b.z; t[7]=b.w;
}
__device__ __forceinline__ bh8 pack8(const float* v){
  bh8 r;
  #pragma unroll
  for (int j = 0; j < 8; ++j) r[j] = (short)f2b(v[j]);
  return r;
}

// ---------------- K1: MFMA MLP + coords prep + keep_coords (R12-identical) ----------------
__global__ __launch_bounds__(256) void mlp_prep_k(const float* __restrict__ feat,
                                                  const float* __restrict__ w1,
                                                  const float* __restrict__ g1,
                                                  const float* __restrict__ b1,
                                                  const float* __restrict__ w2,
                                                  const float* __restrict__ g2,
                                                  const float* __restrict__ b2,
                                                  uint* __restrict__ fBw,
                                                  const float* __restrict__ coords,
                                                  const int* __restrict__ keep,
                                                  float4* __restrict__ cF,
                                                  float* __restrict__ out0){
  int blk = blockIdx.x;
  int tid = threadIdx.x;
  if (blk >= 256){
    if (blk < 512){
      int e = (blk - 256) * 256 + tid;         // e = l*8+n, e < 65536
      int l = e >> 3, n = e & 7;
      const float* cr = coords + (size_t)e * 3;
      float x = cr[0], y = cr[1], z = cr[2];
      float cc;
      {
        #pragma clang fp contract(off)
        cc = x*x + y*y + z*z;                  // matches np sum(c*c,-1): (xx+yy)+zz
      }
      cF[n * L_ + l] = make_float4(x, y, z, cc);
    } else {
      int t = (blk - 512) * 256 + tid;         // t < 49152 = L2*N*3
      int i = t / 24; int rem = t - i * 24;    // (n*3+c)
      out0[t] = coords[(size_t)keep[i] * 24 + rem];
    }
    return;
  }

  __shared__ ushort hlds[64 * 136];            // 17.4 KB; wave wv owns rows [16wv,16wv+16)
  int lane = tid & 63;
  int wv = __builtin_amdgcn_readfirstlane(tid >> 6);
  int quad = lane >> 4, c = lane & 15;
  int rowg = blk * 64 + wv * 16;               // wave's first row (row = n*2048 + l)

  bh8 a1[2];
  {
    int rg = rowg + c; int l = rg & 2047, nb = rg >> 11;
    const float* xr = feat + (size_t)((l << 3) + nb) * 64 + quad * 8;
    float t[8];
    ld8(t, xr);      a1[0] = pack8(t);
    ld8(t, xr + 32); a1[1] = pack8(t);
  }

  f32x4 acc1[8];
  #pragma unroll
  for (int t = 0; t < 8; ++t) acc1[t] = (f32x4){0.f, 0.f, 0.f, 0.f};
  #pragma unroll
  for (int s = 0; s < 2; ++s){
    #pragma unroll
    for (int t = 0; t < 8; ++t){
      float tmp[8];
      ld8(tmp, w1 + (size_t)(t * 16 + c) * 64 + s * 32 + quad * 8);
      acc1[t] = __builtin_amdgcn_mfma_f32_16x16x32_bf16(a1[s], pack8(tmp), acc1[t], 0, 0, 0);
    }
  }

  float mean1[4], rstd1[4];
  #pragma unroll
  for (int r = 0; r < 4; ++r){
    float s = 0.f;
    #pragma unroll
    for (int t = 0; t < 8; ++t) s += acc1[t][r];
    #pragma unroll
    for (int m = 1; m < 16; m <<= 1) s += __shfl_xor(s, m, 16);
    mean1[r] = s * 0.0078125f;
  }
  #pragma unroll
  for (int r = 0; r < 4; ++r){
    float s = 0.f;
    #pragma unroll
    for (int t = 0; t < 8; ++t){ float d = acc1[t][r] - mean1[r]; s += d * d; }
    #pragma unroll
    for (int m = 1; m < 16; m <<= 1) s += __shfl_xor(s, m, 16);
    rstd1[r] = rsqrtf(s * 0.0078125f + 1e-5f);
  }
  ushort* hl = hlds + wv * 16 * 136;
  #pragma unroll
  for (int t = 0; t < 8; ++t){
    float gv = g1[t * 16 + c], bv = b1[t * 16 + c];
    #pragma unroll
    for (int r = 0; r < 4; ++r){
      float v = (acc1[t][r] - mean1[r]) * rstd1[r] * gv + bv;
      hl[(quad * 4 + r) * 136 + t * 16 + c] = f2b(v);
    }
  }

  f32x4 acc2[8];
  #pragma unroll
  for (int t = 0; t < 8; ++t) acc2[t] = (f32x4){0.f, 0.f, 0.f, 0.f};
  #pragma unroll
  for (int s = 0; s < 4; ++s){
    bh8 af = *(const bh8*)(hl + c * 136 + s * 32 + quad * 8);   // 16B-aligned
    #pragma unroll
    for (int t = 0; t < 8; ++t){
      float tmp[8];
      ld8(tmp, w2 + (size_t)(t * 16 + c) * 128 + s * 32 + quad * 8);
      acc2[t] = __builtin_amdgcn_mfma_f32_16x16x32_bf16(af, pack8(tmp), acc2[t], 0, 0, 0);
    }
  }

  float mean2[4], rstd2[4];
  #pragma unroll
  for (int r = 0; r < 4; ++r){
    float s = 0.f;
    #pragma unroll
    for (int t = 0; t < 8; ++t) s += acc2[t][r];
    #pragma unroll
    for (int m = 1; m < 16; m <<= 1) s += __shfl_xor(s, m, 16);
    mean2[r] = s * 0.0078125f;
  }
  #pragma unroll
  for (int r = 0; r < 4; ++r){
    float s = 0.f;
    #pragma unroll
    for (int t = 0; t < 8; ++t){ float d = acc2[t][r] - mean2[r]; s += d * d; }
    #pragma unroll
    for (int m = 1; m < 16; m <<= 1) s += __shfl_xor(s, m, 16);
    rstd2[r] = rsqrtf(s * 0.0078125f + 1e-5f);
  }
  #pragma unroll
  for (int t = 0; t < 8; ++t){
    float gv = g2[t * 16 + c], bv = b2[t * 16 + c];
    #pragma unroll
    for (int r = 0; r < 4; ++r){
      float v = fmaxf((acc2[t][r] - mean2[r]) * rstd2[r] * gv + bv, 0.f);
      hl[(quad * 4 + r) * 136 + t * 16 + c] = f2b(v);
    }
  }

  {
    int row16 = lane >> 2, chunk = lane & 3;
    const uint* src = (const uint*)hlds + (wv * 16 + row16) * 68 + chunk * 16;
    uint* dst = fBw + (size_t)(rowg + row16) * 64 + chunk * 16;
    #pragma unroll
    for (int j = 0; j < 4; ++j)
      *(uint4*)(dst + j * 4) = *(const uint4*)(src + j * 4);
  }
}

// ---------------- K2: fused KNN + pool, 2 queries per wave ----------------
__device__ __forceinline__ u64 shfl64(u64 v, int src){
  int lo = __shfl((int)(uint)v, src, 64);
  int hi = __shfl((int)(uint)(v >> 32), src, 64);
  return ((u64)(uint)hi << 32) | (uint)lo;
}

__device__ __forceinline__ u64 bsort64(u64 key, int lane){
  #pragma unroll
  for (int k = 2; k <= 64; k <<= 1){
    #pragma unroll
    for (int j = k >> 1; j > 0; j >>= 1){
      u64 o = shfl64(key, lane ^ j);
      bool lower = (lane & j) == 0;
      bool down  = (lane & k) == 0;
      bool takeMin = (lower == down);
      bool oLess = o < key;
      key = (oLess == takeMin) ? o : key;
    }
  }
  return key;
}
__device__ __forceinline__ u64 bmerge64(u64 key, int lane){
  #pragma unroll
  for (int j = 32; j > 0; j >>= 1){
    u64 o = shfl64(key, lane ^ j);
    bool lower = (lane & j) == 0;
    bool oLess = o < key;
    key = (oLess == lower) ? o : key;
  }
  return key;
}

__device__ __forceinline__ u64 drain(u64* ldsq, int& qcount, float& hf, int lane){
  u64 a = (lane < qcount) ? ldsq[lane] : ~0ull;
  a = bsort64(a, lane);
  if (qcount > 64){
    u64 b = (64 + lane < qcount) ? ldsq[64 + lane] : ~0ull;
    b = bsort64(b, lane);
    u64 br = shfl64(b, 63 - lane);
    a = a < br ? a : br;
    a = bmerge64(a, lane);
  }
  if (lane < 16) ldsq[lane] = a;
  u64 h = shfl64(a, 15);
  hf = unford((uint)(h >> 32));
  qcount = 16;
  return a;
}

// block = 256 (4 waves); wave = queries g0,g0+1 (same n); lane = candidate-in-batch.
// Each candidate batch load is amortized over 2 queries (halves L2 traffic/query).
__global__ __launch_bounds__(256) void knn_pool_k(const float4* __restrict__ cF,
                                                  const int* __restrict__ keep,
                                                  const uint* __restrict__ fB32,
                                                  float* __restrict__ out1){
  __shared__ u64 q8[4][2][128];         // 8 KB: 2 survivor queues per wave
  int tid = threadIdx.x, lane = tid & 63;
  int wv = tid >> 6;
  int g0 = blockIdx.x * 8 + wv * 2;     // first query id; block spans 8 queries, one n
  int n = g0 >> 11;
  int i0 = g0 & 2047, i1 = i0 + 1;
  u64* qlA = q8[wv][0];
  u64* qlB = q8[wv][1];
  float4 qa = cF[(n << 13) + keep[i0]];
  float4 qb = cF[(n << 13) + keep[i1]];
  const float4* base = cF + (n << 13);

  float hfA = 3.4e38f, hfrA = 3.4e38f; int qcA = 0;
  float hfB = 3.4e38f, hfrB = 3.4e38f; int qcB = 0;

  // two-query filter: one candidate load feeds both tests
  #define PROC2(cf, jidx) { \
    float dA = __builtin_fmaf(qa.x,(cf).x, __builtin_fmaf(qa.y,(cf).y, qa.z*(cf).z)); \
    float dB = __builtin_fmaf(qb.x,(cf).x, __builtin_fmaf(qb.y,(cf).y, qb.z*(cf).z)); \
    float eA = __builtin_fmaf(-2.0f, dA, qa.w + (cf).w); \
    float eB = __builtin_fmaf(-2.0f, dB, qb.w + (cf).w); \
    u64 balA = __ballot(eA <= hfrA); \
    u64 balB = __ballot(eB <= hfrB); \
    if (balA){ \
      if (eA <= hfrA){ \
        float d2; \
        { \
          _Pragma("clang fp contract(off)") \
          float dot = qa.x*(cf).x + qa.y*(cf).y + qa.z*(cf).z; \
          d2 = (qa.w + (cf).w) - 2.0f * dot; \
        } \
        int rel = __builtin_amdgcn_mbcnt_lo((uint)balA, 0); \
        rel = __builtin_amdgcn_mbcnt_hi((uint)(balA >> 32), rel); \
        qlA[qcA + rel] = ((u64)ford(d2) << 32) | (uint)(jidx); \
      } \
      qcA += __popcll(balA); \
      if (qcA >= 49){ drain(qlA, qcA, hfA, lane); hfrA = hfA + 1e-3f; } \
    } \
    if (balB){ \
      if (eB <= hfrB){ \
        float d2; \
        { \
          _Pragma("clang fp contract(off)") \
          float dot = qb.x*(cf).x + qb.y*(cf).y + qb.z*(cf).z; \
          d2 = (qb.w + (cf).w) - 2.0f * dot; \
        } \
        int rel = __builtin_amdgcn_mbcnt_lo((uint)balB, 0); \
        rel = __builtin_amdgcn_mbcnt_hi((uint)(balB >> 32), rel); \
        qlB[qcB + rel] = ((u64)ford(d2) << 32) | (uint)(jidx); \
      } \
      qcB += __popcll(balB); \
      if (qcB >= 49){ drain(qlB, qcB, hfB, lane); hfrB = hfB + 1e-3f; } \
    } \
  }

  for (int b = 0; b < 128; b += 4){
    const float4* p = base + (b << 6) + lane;
    float4 c0 = p[0];
    float4 c1 = p[64];
    float4 c2 = p[128];
    float4 c3 = p[192];
    int j0 = (b << 6) + lane;
    PROC2(c0, j0);
    PROC2(c1, j0 + 64);
    PROC2(c2, j0 + 128);
    PROC2(c3, j0 + 192);
  }
  u64 aA = drain(qlA, qcA, hfA, lane);
  u64 aB = drain(qlB, qcB, hfB, lane);
  #undef PROC2

  // fused pool for both queries
  const uint* frow = fB32 + ((size_t)(n << 11) << 6);
  float a0 = -3.4e38f, a1v = -3.4e38f, b0 = -3.4e38f, b1v = -3.4e38f;
  #pragma unroll
  for (int k = 0; k < 16; ++k){
    int idxA = (int)(shfl64(aA, k) & 2047u);            // fmod(L2) quirk
    int idxB = (int)(shfl64(aB, k) & 2047u);
    uint uA = frow[((size_t)idxA << 6) + lane];
    uint uB = frow[((size_t)idxB << 6) + lane];
    a0  = fmaxf(a0,  __uint_as_float((uA & 0xFFFFu) << 16));
    a1v = fmaxf(a1v, __uint_as_float((uA >> 16) << 16));
    b0  = fmaxf(b0,  __uint_as_float((uB & 0xFFFFu) << 16));
    b1v = fmaxf(b1v, __uint_as_float((uB >> 16) << 16));
  }
  float2* oA = (float2*)(out1 + (size_t)(i0 * 8 + n) * 128);
  float2* oB = (float2*)(out1 + (size_t)(i1 * 8 + n) * 128);
  oA[lane] = make_float2(a0, a1v);
  oB[lane] = make_float2(b0, b1v);
}

extern "C" void kernel_launch(void* const* d_in, const int* in_sizes, int n_in,
                              void* d_out, int out_size, void* d_ws, size_t ws_size,
                              hipStream_t stream){
  const float* coords = (const float*)d_in[0];
  const float* feat   = (const float*)d_in[1];
  const float* w1     = (const float*)d_in[2];
  const float* g1     = (const float*)d_in[3];
  const float* b1     = (const float*)d_in[4];
  const float* w2     = (const float*)d_in[5];
  const float* g2     = (const float*)d_in[6];
  const float* b2     = (const float*)d_in[7];
  const int*   keep   = (const int*)d_in[8];
  float* out0 = (float*)d_out;                    // keep_coords [2048,8,3]
  float* out1 = out0 + 49152;                     // pool_features [2048,8,128]

  char* ws = (char*)d_ws;
  float4* cF = (float4*)ws;                       // [N][L] f32x4 : 1 MB
  ushort* fB = (ushort*)(ws + (1 << 20));         // [N][L2][128] bf16 : 4 MB

  hipLaunchKernelGGL(mlp_prep_k, dim3(704), dim3(256), 0, stream,
                     feat, w1, g1, b1, w2, g2, b2, (uint*)fB, coords, keep, cF, out0);
  hipLaunchKernelGGL(knn_pool_k, dim3(2048), dim3(256), 0, stream,
                     cF, keep, (const uint*)fB, out1);
}

// Round 14
// 177.039 us; speedup vs baseline: 1.4661x; 1.0137x over previous
//
#include <hip/hip_runtime.h>
#include <stdint.h>

// Problem constants
#define L_    8192
#define N_    8
#define L2_   2048
#define K_    16

typedef unsigned int uint;
typedef unsigned short ushort;
typedef unsigned long long u64;
typedef __attribute__((ext_vector_type(8))) short bh8;   // 8 bf16 (4 VGPRs)
typedef __attribute__((ext_vector_type(4))) float f32x4; // MFMA C/D

// round-to-nearest-even f32 -> bf16 (monotone)
__device__ __forceinline__ ushort f2b(float f){
  uint u = __float_as_uint(f);
  return (ushort)((u + 0x7FFFu + ((u >> 16) & 1u)) >> 16);
}
// monotone float->uint mapping (handles tiny negative self-distances)
__device__ __forceinline__ uint ford(float f){
  uint u = __float_as_uint(f);
  return u ^ ((uint)((int)u >> 31) | 0x80000000u);
}
// inverse of ford
__device__ __forceinline__ float unford(uint u){
  uint v = (u & 0x80000000u) ? (u ^ 0x80000000u) : ~u;
  return __uint_as_float(v);
}

__device__ __forceinline__ void ld8(float* t, const float* p){
  float4 a = *(const float4*)p; float4 b = *(const float4*)(p + 4);
  t[0]=a.x; t[1]=a.y; t[2]=a.z; t[3]=a.w; t[4]=b.x; t[5]=b.y; t[6]=b.z; t[7]=b.w;
}
__device__ __forceinline__ bh8 pack8(const float* v){
  bh8 r;
  #pragma unroll
  for (int j = 0; j < 8; ++j) r[j] = (short)f2b(v[j]);
  return r;
}

// ---------------- K0: prep (cF, keep_coords) + weight pre-pack ----------------
// blocks [0,96): pack w1 (8192) + w2 (16384) f32 -> bf16, 1 elem/thread
// blocks [96,352): cF build. blocks [352,544): keep_coords gather.
__global__ __launch_bounds__(256) void prep_pack_k(const float* __restrict__ coords,
                                                   const int* __restrict__ keep,
                                                   const float* __restrict__ w1,
                                                   const float* __restrict__ w2,
                                                   float4* __restrict__ cF,
                                                   float* __restrict__ out0,
                                                   ushort* __restrict__ pw1,
                                                   ushort* __restrict__ pw2){
  int blk = blockIdx.x;
  int tid = threadIdx.x;
  if (blk < 96){
    int e = blk * 256 + tid;                   // e < 24576 = 8192 + 16384
    if (e < 8192) pw1[e] = f2b(w1[e]);
    else          pw2[e - 8192] = f2b(w2[e - 8192]);
  } else if (blk < 352){
    int e = (blk - 96) * 256 + tid;            // e = l*8+n, e < 65536
    int l = e >> 3, n = e & 7;
    const float* cr = coords + (size_t)e * 3;
    float x = cr[0], y = cr[1], z = cr[2];
    float cc;
    {
      #pragma clang fp contract(off)
      cc = x*x + y*y + z*z;                    // matches np sum(c*c,-1): (xx+yy)+zz
    }
    cF[n * L_ + l] = make_float4(x, y, z, cc);
  } else {
    int t = (blk - 352) * 256 + tid;           // t < 49152 = L2*N*3
    int i = t / 24; int rem = t - i * 24;      // (n*3+c)
    out0[t] = coords[(size_t)keep[i] * 24 + rem];
  }
}

// ---------------- K1: MFMA MLP (pre-packed bf16 weights) ----------------
// grid 256, block 256 = 4 independent waves; wave = 16 rows x 128 dims.
// GEMM inner loops: pure bh8 global load (L1-hot after first use) + MFMA.
__global__ __launch_bounds__(256) void mlp_k(const float* __restrict__ feat,
                                             const ushort* __restrict__ pw1,
                                             const float* __restrict__ g1,
                                             const float* __restrict__ b1,
                                             const ushort* __restrict__ pw2,
                                             const float* __restrict__ g2,
                                             const float* __restrict__ b2,
                                             uint* __restrict__ fBw){
  __shared__ ushort hlds[64 * 136];            // 17.4 KB; wave wv owns rows [16wv,16wv+16)
  int tid = threadIdx.x;
  int lane = tid & 63;
  int wv = __builtin_amdgcn_readfirstlane(tid >> 6);
  int quad = lane >> 4, c = lane & 15;
  int rowg = blockIdx.x * 64 + wv * 16;        // wave's first row (row = n*2048 + l)

  // A-frags for GEMM1: x[rowg+c][s*32 + quad*8 + j], s=0,1
  bh8 a1[2];
  {
    int rg = rowg + c; int l = rg & 2047, nb = rg >> 11;
    const float* xr = feat + (size_t)((l << 3) + nb) * 64 + quad * 8;
    float t[8];
    ld8(t, xr);      a1[0] = pack8(t);
    ld8(t, xr + 32); a1[1] = pack8(t);
  }

  // GEMM1: h[m][n] = sum_k x[m][k] w1[n][k]
  f32x4 acc1[8];
  #pragma unroll
  for (int t = 0; t < 8; ++t) acc1[t] = (f32x4){0.f, 0.f, 0.f, 0.f};
  #pragma unroll
  for (int s = 0; s < 2; ++s){
    #pragma unroll
    for (int t = 0; t < 8; ++t){
      bh8 wb = *(const bh8*)(pw1 + (size_t)(t * 16 + c) * 64 + s * 32 + quad * 8);
      acc1[t] = __builtin_amdgcn_mfma_f32_16x16x32_bf16(a1[s], wb, acc1[t], 0, 0, 0);
    }
  }

  // LN1 in-register: row m = quad*4+r lives in the 16 lanes of this quad
  float mean1[4], rstd1[4];
  #pragma unroll
  for (int r = 0; r < 4; ++r){
    float s = 0.f;
    #pragma unroll
    for (int t = 0; t < 8; ++t) s += acc1[t][r];
    #pragma unroll
    for (int m = 1; m < 16; m <<= 1) s += __shfl_xor(s, m, 16);
    mean1[r] = s * 0.0078125f;
  }
  #pragma unroll
  for (int r = 0; r < 4; ++r){
    float s = 0.f;
    #pragma unroll
    for (int t = 0; t < 8; ++t){ float d = acc1[t][r] - mean1[r]; s += d * d; }
    #pragma unroll
    for (int m = 1; m < 16; m <<= 1) s += __shfl_xor(s, m, 16);
    rstd1[r] = rsqrtf(s * 0.0078125f + 1e-5f);
  }
  ushort* hl = hlds + wv * 16 * 136;
  #pragma unroll
  for (int t = 0; t < 8; ++t){
    float gv = g1[t * 16 + c], bv = b1[t * 16 + c];
    #pragma unroll
    for (int r = 0; r < 4; ++r){
      float v = (acc1[t][r] - mean1[r]) * rstd1[r] * gv + bv;
      hl[(quad * 4 + r) * 136 + t * 16 + c] = f2b(v);
    }
  }

  // GEMM2: A-frags from LDS (layout transform), B = packed w2
  f32x4 acc2[8];
  #pragma unroll
  for (int t = 0; t < 8; ++t) acc2[t] = (f32x4){0.f, 0.f, 0.f, 0.f};
  #pragma unroll
  for (int s = 0; s < 4; ++s){
    bh8 af = *(const bh8*)(hl + c * 136 + s * 32 + quad * 8);   // 16B-aligned
    #pragma unroll
    for (int t = 0; t < 8; ++t){
      bh8 wb = *(const bh8*)(pw2 + (size_t)(t * 16 + c) * 128 + s * 32 + quad * 8);
      acc2[t] = __builtin_amdgcn_mfma_f32_16x16x32_bf16(af, wb, acc2[t], 0, 0, 0);
    }
  }

  // LN2 + ReLU
  float mean2[4], rstd2[4];
  #pragma unroll
  for (int r = 0; r < 4; ++r){
    float s = 0.f;
    #pragma unroll
    for (int t = 0; t < 8; ++t) s += acc2[t][r];
    #pragma unroll
    for (int m = 1; m < 16; m <<= 1) s += __shfl_xor(s, m, 16);
    mean2[r] = s * 0.0078125f;
  }
  #pragma unroll
  for (int r = 0; r < 4; ++r){
    float s = 0.f;
    #pragma unroll
    for (int t = 0; t < 8; ++t){ float d = acc2[t][r] - mean2[r]; s += d * d; }
    #pragma unroll
    for (int m = 1; m < 16; m <<= 1) s += __shfl_xor(s, m, 16);
    rstd2[r] = rsqrtf(s * 0.0078125f + 1e-5f);
  }
  #pragma unroll
  for (int t = 0; t < 8; ++t){
    float gv = g2[t * 16 + c], bv = b2[t * 16 + c];
    #pragma unroll
    for (int r = 0; r < 4; ++r){
      float v = fmaxf((acc2[t][r] - mean2[r]) * rstd2[r] * gv + bv, 0.f);
      hl[(quad * 4 + r) * 136 + t * 16 + c] = f2b(v);
    }
  }

  // coalesced store: lane -> row16 = lane>>2, dword-chunk = lane&3
  {
    int row16 = lane >> 2, chunk = lane & 3;
    const uint* src = (const uint*)hlds + (wv * 16 + row16) * 68 + chunk * 16;
    uint* dst = fBw + (size_t)(rowg + row16) * 64 + chunk * 16;
    #pragma unroll
    for (int j = 0; j < 4; ++j)
      *(uint4*)(dst + j * 4) = *(const uint4*)(src + j * 4);
  }
}

// ---------------- K2: fused KNN + pool, 2 queries per wave (R13-identical) ----------------
__device__ __forceinline__ u64 shfl64(u64 v, int src){
  int lo = __shfl((int)(uint)v, src, 64);
  int hi = __shfl((int)(uint)(v >> 32), src, 64);
  return ((u64)(uint)hi << 32) | (uint)lo;
}

__device__ __forceinline__ u64 bsort64(u64 key, int lane){
  #pragma unroll
  for (int k = 2; k <= 64; k <<= 1){
    #pragma unroll
    for (int j = k >> 1; j > 0; j >>= 1){
      u64 o = shfl64(key, lane ^ j);
      bool lower = (lane & j) == 0;
      bool down  = (lane & k) == 0;
      bool takeMin = (lower == down);
      bool oLess = o < key;
      key = (oLess == takeMin) ? o : key;
    }
  }
  return key;
}
__device__ __forceinline__ u64 bmerge64(u64 key, int lane){
  #pragma unroll
  for (int j = 32; j > 0; j >>= 1){
    u64 o = shfl64(key, lane ^ j);
    bool lower = (lane & j) == 0;
    bool oLess = o < key;
    key = (oLess == lower) ? o : key;
  }
  return key;
}

__device__ __forceinline__ u64 drain(u64* ldsq, int& qcount, float& hf, int lane){
  u64 a = (lane < qcount) ? ldsq[lane] : ~0ull;
  a = bsort64(a, lane);
  if (qcount > 64){
    u64 b = (64 + lane < qcount) ? ldsq[64 + lane] : ~0ull;
    b = bsort64(b, lane);
    u64 br = shfl64(b, 63 - lane);
    a = a < br ? a : br;
    a = bmerge64(a, lane);
  }
  if (lane < 16) ldsq[lane] = a;
  u64 h = shfl64(a, 15);
  hf = unford((uint)(h >> 32));
  qcount = 16;
  return a;
}

__global__ __launch_bounds__(256) void knn_pool_k(const float4* __restrict__ cF,
                                                  const int* __restrict__ keep,
                                                  const uint* __restrict__ fB32,
                                                  float* __restrict__ out1){
  __shared__ u64 q8[4][2][128];         // 8 KB: 2 survivor queues per wave
  int tid = threadIdx.x, lane = tid & 63;
  int wv = tid >> 6;
  int g0 = blockIdx.x * 8 + wv * 2;     // first query id; block spans 8 queries, one n
  int n = g0 >> 11;
  int i0 = g0 & 2047, i1 = i0 + 1;
  u64* qlA = q8[wv][0];
  u64* qlB = q8[wv][1];
  float4 qa = cF[(n << 13) + keep[i0]];
  float4 qb = cF[(n << 13) + keep[i1]];
  const float4* base = cF + (n << 13);

  float hfA = 3.4e38f, hfrA = 3.4e38f; int qcA = 0;
  float hfB = 3.4e38f, hfrB = 3.4e38f; int qcB = 0;

  #define PROC2(cf, jidx) { \
    float dA = __builtin_fmaf(qa.x,(cf).x, __builtin_fmaf(qa.y,(cf).y, qa.z*(cf).z)); \
    float dB = __builtin_fmaf(qb.x,(cf).x, __builtin_fmaf(qb.y,(cf).y, qb.z*(cf).z)); \
    float eA = __builtin_fmaf(-2.0f, dA, qa.w + (cf).w); \
    float eB = __builtin_fmaf(-2.0f, dB, qb.w + (cf).w); \
    u64 balA = __ballot(eA <= hfrA); \
    u64 balB = __ballot(eB <= hfrB); \
    if (balA){ \
      if (eA <= hfrA){ \
        float d2; \
        { \
          _Pragma("clang fp contract(off)") \
          float dot = qa.x*(cf).x + qa.y*(cf).y + qa.z*(cf).z; \
          d2 = (qa.w + (cf).w) - 2.0f * dot; \
        } \
        int rel = __builtin_amdgcn_mbcnt_lo((uint)balA, 0); \
        rel = __builtin_amdgcn_mbcnt_hi((uint)(balA >> 32), rel); \
        qlA[qcA + rel] = ((u64)ford(d2) << 32) | (uint)(jidx); \
      } \
      qcA += __popcll(balA); \
      if (qcA >= 49){ drain(qlA, qcA, hfA, lane); hfrA = hfA + 1e-3f; } \
    } \
    if (balB){ \
      if (eB <= hfrB){ \
        float d2; \
        { \
          _Pragma("clang fp contract(off)") \
          float dot = qb.x*(cf).x + qb.y*(cf).y + qb.z*(cf).z; \
          d2 = (qb.w + (cf).w) - 2.0f * dot; \
        } \
        int rel = __builtin_amdgcn_mbcnt_lo((uint)balB, 0); \
        rel = __builtin_amdgcn_mbcnt_hi((uint)(balB >> 32), rel); \
        qlB[qcB + rel] = ((u64)ford(d2) << 32) | (uint)(jidx); \
      } \
      qcB += __popcll(balB); \
      if (qcB >= 49){ drain(qlB, qcB, hfB, lane); hfrB = hfB + 1e-3f; } \
    } \
  }

  for (int b = 0; b < 128; b += 4){
    const float4* p = base + (b << 6) + lane;
    float4 c0 = p[0];
    float4 c1 = p[64];
    float4 c2 = p[128];
    float4 c3 = p[192];
    int j0 = (b << 6) + lane;
    PROC2(c0, j0);
    PROC2(c1, j0 + 64);
    PROC2(c2, j0 + 128);
    PROC2(c3, j0 + 192);
  }
  u64 aA = drain(qlA, qcA, hfA, lane);
  u64 aB = drain(qlB, qcB, hfB, lane);
  #undef PROC2

  const uint* frow = fB32 + ((size_t)(n << 11) << 6);
  float a0 = -3.4e38f, a1v = -3.4e38f, b0 = -3.4e38f, b1v = -3.4e38f;
  #pragma unroll
  for (int k = 0; k < 16; ++k){
    int idxA = (int)(shfl64(aA, k) & 2047u);            // fmod(L2) quirk
    int idxB = (int)(shfl64(aB, k) & 2047u);
    uint uA = frow[((size_t)idxA << 6) + lane];
    uint uB = frow[((size_t)idxB << 6) + lane];
    a0  = fmaxf(a0,  __uint_as_float((uA & 0xFFFFu) << 16));
    a1v = fmaxf(a1v, __uint_as_float((uA >> 16) << 16));
    b0  = fmaxf(b0,  __uint_as_float((uB & 0xFFFFu) << 16));
    b1v = fmaxf(b1v, __uint_as_float((uB >> 16) << 16));
  }
  float2* oA = (float2*)(out1 + (size_t)(i0 * 8 + n) * 128);
  float2* oB = (float2*)(out1 + (size_t)(i1 * 8 + n) * 128);
  oA[lane] = make_float2(a0, a1v);
  oB[lane] = make_float2(b0, b1v);
}

extern "C" void kernel_launch(void* const* d_in, const int* in_sizes, int n_in,
                              void* d_out, int out_size, void* d_ws, size_t ws_size,
                              hipStream_t stream){
  const float* coords = (const float*)d_in[0];
  const float* feat   = (const float*)d_in[1];
  const float* w1     = (const float*)d_in[2];
  const float* g1     = (const float*)d_in[3];
  const float* b1     = (const float*)d_in[4];
  const float* w2     = (const float*)d_in[5];
  const float* g2     = (const float*)d_in[6];
  const float* b2     = (const float*)d_in[7];
  const int*   keep   = (const int*)d_in[8];
  float* out0 = (float*)d_out;                    // keep_coords [2048,8,3]
  float* out1 = out0 + 49152;                     // pool_features [2048,8,128]

  char* ws = (char*)d_ws;
  float4* cF  = (float4*)ws;                      // [N][L] f32x4 : 1 MB
  ushort* fB  = (ushort*)(ws + (1 << 20));        // [N][L2][128] bf16 : 4 MB
  ushort* pw1 = (ushort*)(ws + (5 << 20));        // 16 KB packed w1
  ushort* pw2 = pw1 + 8192;                       // 32 KB packed w2

  hipLaunchKernelGGL(prep_pack_k, dim3(544), dim3(256), 0, stream,
                     coords, keep, w1, w2, cF, out0, pw1, pw2);
  hipLaunchKernelGGL(mlp_k, dim3(256), dim3(256), 0, stream,
                     feat, pw1, g1, b1, pw2, g2, b2, (uint*)fB);
  hipLaunchKernelGGL(knn_pool_k, dim3(2048), dim3(256), 0, stream,
                     cF, keep, (const uint*)fB, out1);
}